// Round 4
// baseline (307.095 us; speedup 1.0000x reference)
//
#include <hip/hip_runtime.h>
#include <cstdint>

// GCN forward on MI355X (gfx950). f32 in/out; bf16 MFMA with fp32 accum;
// bf16 intermediates; 4-byte packed fixed-stride CSR (src:u16 | weight:bf16).
// Round 13: role-merged scatter+gemm1.
//  - R3's block-partitioned fusion gave zero overlap (86.6us ~= serial sum):
//    scatter blocks stall on 8-deep atomic chains while gemm1 blocks queue.
//    The 800k atomicAdd-with-return stream is throughput-bound (~6/cyc chip-
//    wide ~= 55-60us) and padding didn't change it -> hide the GEMM under it.
//  - Every gemm1 block now scatters its own 1024-edge slice (4 edges/thread)
//    before its GEMM tile; 782 blocks fit one residency round (4/CU x 256).
// Chain (5): prep0 -> [scatter-in-gemm1 blocks] -> spmm1+bias+relu -> gemm2
//   -> spmm2+bias+log_softmax.

typedef unsigned short u16;
typedef unsigned int u32;
typedef __attribute__((ext_vector_type(8))) short bf16x8;
typedef __attribute__((ext_vector_type(4))) float f32x4;

#define N_NODES 50000
#define N_EDGES 800000
#define NFEAT 512
#define NHID 256
#define NCLASS 64
#define CSTRIDE 64        // fixed CSR slots per node (max deg << 64)
#define DEGS 16           // deg stride in ints: one counter per 64B line

#define GB1 782           // gemm1 blocks: ceil(50000/64); also scatter slices
#define EPB 1024          // edges per gemm1 block (782*1024 >= 800000)
#define PW1B 512          // W1T transpose blocks
#define PW2B 64           // W2T transpose blocks
#define DEGZB 196         // deg-zero blocks: ceil(800000 ints / 4096)

__device__ __forceinline__ float bf2f(u16 h) {
    union { u32 u; float f; } c; c.u = ((u32)h) << 16; return c.f;
}
__device__ __forceinline__ u16 f2bf(float f) {
    union { float f; u32 u; } c; c.f = f;
    u32 u = c.u;
    return (u16)((u + 0x7fffu + ((u >> 16) & 1u)) >> 16);   // RNE
}
__device__ __forceinline__ u32 pk2(float a, float b) {
    return (u32)f2bf(a) | ((u32)f2bf(b) << 16);
}

// async global->LDS, 16B per lane; LDS dest = wave-uniform base + lane*16.
__device__ __forceinline__ void async16(const void* g, void* l) {
    __builtin_amdgcn_global_load_lds(
        (const __attribute__((address_space(1))) void*)(uintptr_t)g,
        (__attribute__((address_space(3))) void*)(uintptr_t)l, 16, 0, 0);
}

// ---------------- prep0: W1/W2 transpose+cvt + deg zeroing ----------------
// blocks [0,PW1B): W1T. [PW1B,PW1B+PW2B): W2T. rest: zero deg (16 ints/thread).

__global__ __launch_bounds__(256) void prep0_kernel(
    const float* __restrict__ W1, u16* __restrict__ W1T,
    const float* __restrict__ W2, u16* __restrict__ W2T,
    int* __restrict__ deg) {
    int b = blockIdx.x;
    if (b < PW1B) {
        int idx = b * 256 + threadIdx.x;           // W1T[256][512]
        int n = idx >> 9, k = idx & 511;
        W1T[idx] = f2bf(W1[(size_t)k * NHID + n]);
    } else if (b < PW1B + PW2B) {
        int idx = (b - PW1B) * 256 + threadIdx.x;  // W2T[64][256]
        int n = idx >> 8, k = idx & 255;
        W2T[idx] = f2bf(W2[(size_t)k * NCLASS + n]);
    } else {
        int base = (b - PW1B - PW2B) * 4096 + threadIdx.x * 16;
        if (base < N_NODES * DEGS) {               // 800000 % 16 == 0: full chunk
            int4 z = make_int4(0, 0, 0, 0);
            int4* p = (int4*)(deg + base);
            p[0] = z; p[1] = z; p[2] = z; p[3] = z;
        }
    }
}

// ---------------- shared GEMM body: C[M,NT] = A[M,K] @ BT[NT][K]^T ----------------
// Tiles in LDS are [row][64] u16 with the 16B-chunk index XOR-swizzled by row&7
// (T2). Async-staged operands keep the LDS dest linear and permute the global
// source chunk; the reg-staged (ACVT) A swizzles the ds_write address. Fragment
// reads apply the same XOR. 4 waves WROWSxWCOLS, BK=64 (2 k-halves).
// Epilogue repacks C through LDS.

template <int MT, int NT, int WCOLS, int K, bool ACVT>
__device__ __forceinline__ void gemm_body(const void* __restrict__ Av,
                                          const u16* __restrict__ BT,
                                          u16* __restrict__ C, int M,
                                          int bid, u16* lds) {
    constexpr int WROWS = 4 / WCOLS;
    constexpr int RT = MT / (16 * WROWS);
    constexpr int CT = NT / (16 * WCOLS);
    u16* As = lds;             // [MT][64] swizzled
    u16* Bs = lds + MT * 64;   // [NT][64] swizzled (B^T: row n, k-contig)

    const int tid  = threadIdx.x;
    const int wv   = tid >> 6, lane = tid & 63;
    const int lm   = lane & 15, quad = lane >> 4;
    const int wrow = wv / WCOLS, wcol = wv % WCOLS;
    const int m0   = bid * MT;
    // swizzled in-row u16 offsets for the 2 k-halves (row-bases are 0 mod 8,
    // so row&7 == lm&7 for every fragment row this lane touches)
    const int co0 = ((0 * 4 + quad) ^ (lm & 7)) * 8;
    const int co1 = ((1 * 4 + quad) ^ (lm & 7)) * 8;

    f32x4 acc[RT][CT];
    #pragma unroll
    for (int r = 0; r < RT; ++r)
        #pragma unroll
        for (int c = 0; c < CT; ++c) acc[r][c] = (f32x4){0.f, 0.f, 0.f, 0.f};

    for (int k0 = 0; k0 < K; k0 += 64) {
        if constexpr (ACVT) {
            static_assert(MT == 64, "ACVT staging assumes MT==64 (16 elems/thread)");
            const float* Af = (const float*)Av;
            // issue A f32 loads first (reg), then B DMA, then pack+write.
            int row = tid >> 2, ko = (tid & 3) * 16;   // ko: u16 offset, chunks 2q,2q+1
            int gr = m0 + row; if (gr > M - 1) gr = M - 1;
            const float4* gp = (const float4*)(Af + (size_t)gr * K + k0 + ko);
            float4 f0 = gp[0], f1 = gp[1], f2 = gp[2], f3 = gp[3];
            #pragma unroll
            for (int i = 0; i < NT / 32; ++i) {
                int c = i * 256 + tid;
                int n = c >> 3, kb = c & 7;
                async16(BT + (size_t)n * K + k0 + ((kb ^ (n & 7)) * 8), Bs + c * 8);
            }
            u32 p[8] = {pk2(f0.x, f0.y), pk2(f0.z, f0.w), pk2(f1.x, f1.y), pk2(f1.z, f1.w),
                        pk2(f2.x, f2.y), pk2(f2.z, f2.w), pk2(f3.x, f3.y), pk2(f3.z, f3.w)};
            int ch0 = (2 * (tid & 3))     ^ (row & 7);
            int ch1 = (2 * (tid & 3) + 1) ^ (row & 7);
            *(int4*)(As + row * 64 + ch0 * 8) = *(int4*)&p[0];
            *(int4*)(As + row * 64 + ch1 * 8) = *(int4*)&p[4];
        } else {
            const u16* A = (const u16*)Av;
            #pragma unroll
            for (int i = 0; i < NT / 32; ++i) {
                int c = i * 256 + tid;
                int n = c >> 3, kb = c & 7;
                async16(BT + (size_t)n * K + k0 + ((kb ^ (n & 7)) * 8), Bs + c * 8);
            }
            #pragma unroll
            for (int i = 0; i < MT / 32; ++i) {
                int c = i * 256 + tid;
                int row = c >> 3, kb = c & 7;
                int gr = m0 + row; if (gr > M - 1) gr = M - 1;
                async16(A + (size_t)gr * K + k0 + ((kb ^ (row & 7)) * 8), As + c * 8);
            }
        }
        __syncthreads();   // drains async vmcnt + lgkm (ds_write)

        #pragma unroll
        for (int kk = 0; kk < 2; ++kk) {
            const int co = kk ? co1 : co0;
            bf16x8 af[RT], bfv[CT];
            #pragma unroll
            for (int rt = 0; rt < RT; ++rt) {
                int row = wrow * (RT * 16) + rt * 16 + lm;
                af[rt] = *(const bf16x8*)(As + row * 64 + co);
            }
            #pragma unroll
            for (int ct = 0; ct < CT; ++ct) {
                int n = wcol * CT * 16 + ct * 16 + lm;
                bfv[ct] = *(const bf16x8*)(Bs + n * 64 + co);
            }
            #pragma unroll
            for (int rt = 0; rt < RT; ++rt)
                #pragma unroll
                for (int ct = 0; ct < CT; ++ct)
                    acc[rt][ct] = __builtin_amdgcn_mfma_f32_16x16x32_bf16(
                        af[rt], bfv[ct], acc[rt][ct], 0, 0, 0);
        }
        __syncthreads();
    }

    #pragma unroll
    for (int rt = 0; rt < RT; ++rt)
        #pragma unroll
        for (int ct = 0; ct < CT; ++ct) {
            int col = wcol * CT * 16 + ct * 16 + lm;
            #pragma unroll
            for (int r = 0; r < 4; ++r) {
                int row = wrow * (RT * 16) + rt * 16 + quad * 4 + r;  // C/D: row=quad*4+reg
                lds[row * NT + col] = f2bf(acc[rt][ct][r]);
            }
        }
    __syncthreads();
    constexpr int NC = MT * NT / 2048;
    #pragma unroll
    for (int i = 0; i < NC; ++i) {
        int c = i * 256 + tid;
        int row = (c * 8) / NT;
        if (m0 + row < M)
            *(int4*)(C + (size_t)m0 * NT + c * 8) = *(const int4*)(lds + c * 8);
    }
}

// ---------------- gemm1 with embedded scatter ----------------
// Every block: (1) scatter its 1024-edge slice (4 edges/thread, atomics issued
// up-front; latency hides under other waves' GEMM), (2) gemm1 tile on f32 x.

__global__ __launch_bounds__(256) void gemm1_scatter_kernel(
    const float* __restrict__ x, const u16* __restrict__ W1T, u16* __restrict__ S1,
    const int* __restrict__ esrc, const int* __restrict__ edst,
    const float* __restrict__ ew, int* __restrict__ deg, u32* __restrict__ csr) {
    __shared__ __align__(16) u16 lds[(64 + 256) * 64];
    int b = blockIdx.x;
    int e0 = b * EPB + threadIdx.x * 4;
    if (e0 < N_EDGES) {                           // 800000 % 4 == 0: full chunk
        int4 d4 = *(const int4*)(edst + e0);
        int4 s4 = *(const int4*)(esrc + e0);
        float4 w4 = *(const float4*)(ew + e0);
        int d[4] = {d4.x, d4.y, d4.z, d4.w};
        int s[4] = {s4.x, s4.y, s4.z, s4.w};
        float w[4] = {w4.x, w4.y, w4.z, w4.w};
        int r[4];
        #pragma unroll
        for (int i = 0; i < 4; ++i)               // 4 independent atomics in flight
            r[i] = atomicAdd(&deg[d[i] * DEGS], 1);
        #pragma unroll
        for (int i = 0; i < 4; ++i)
            if (r[i] < CSTRIDE)                   // safety clamp; never hit for this data
                csr[(size_t)d[i] * CSTRIDE + r[i]] = (u32)s[i] | ((u32)f2bf(w[i]) << 16);
    }
    gemm_body<64, 256, 4, NFEAT, true>(x, W1T, S1, N_NODES, b, lds);
}

// ---------------- gemm2: S2[M,64] = H[M,256] @ W2T[64][256]^T ----------------

__global__ __launch_bounds__(256) void gemm2_kernel(const u16* __restrict__ H,
                                                    const u16* __restrict__ W2T,
                                                    u16* __restrict__ S2, int M) {
    __shared__ __align__(16) u16 lds[(128 + 64) * 64];
    gemm_body<128, 64, 2, NHID, false>(H, W2T, S2, M, blockIdx.x, lds);
}

// ---------------- SpMM1 + bias + ReLU (one wave/node, 4 feats/lane, 8-way unroll) ----------------
// csr/deg addressing forced wave-uniform (readfirstlane) -> SMEM loads.

__global__ __launch_bounds__(256) void spmm_bias_relu_kernel(
    const u16* __restrict__ S, const int* __restrict__ deg,
    const u32* __restrict__ csr, const float* __restrict__ bias,
    u16* __restrict__ H, int n) {
    int node = blockIdx.x * 4 + (threadIdx.x >> 6);
    if (node >= n) return;
    node = __builtin_amdgcn_readfirstlane(node);
    int lane = threadIdx.x & 63;
    int beg = node * CSTRIDE;
    int end = beg + deg[node * DEGS];
    float a0 = 0.f, a1 = 0.f, a2 = 0.f, a3 = 0.f;
    int j = beg;
    for (; j + 8 <= end; j += 8) {           // 8 outstanding gathers
        u32 e[8];
        #pragma unroll
        for (int i = 0; i < 8; ++i) e[i] = csr[j + i];   // uniform -> s_load
        ushort4 v[8];
        #pragma unroll
        for (int i = 0; i < 8; ++i)
            v[i] = *(const ushort4*)(S + (size_t)(e[i] & 0xFFFFu) * NHID + lane * 4);
        #pragma unroll
        for (int i = 0; i < 8; ++i) {
            float w = bf2f((u16)(e[i] >> 16));
            a0 += w * bf2f(v[i].x); a1 += w * bf2f(v[i].y);
            a2 += w * bf2f(v[i].z); a3 += w * bf2f(v[i].w);
        }
    }
    for (; j < end; ++j) {
        u32 e0 = csr[j];
        float w = bf2f((u16)(e0 >> 16));
        ushort4 v0 = *(const ushort4*)(S + (size_t)(e0 & 0xFFFFu) * NHID + lane * 4);
        a0 += w * bf2f(v0.x); a1 += w * bf2f(v0.y);
        a2 += w * bf2f(v0.z); a3 += w * bf2f(v0.w);
    }
    float4 bv = *(const float4*)(bias + lane * 4);
    a0 = fmaxf(a0 + bv.x, 0.f);
    a1 = fmaxf(a1 + bv.y, 0.f);
    a2 = fmaxf(a2 + bv.z, 0.f);
    a3 = fmaxf(a3 + bv.w, 0.f);
    ushort4 o;
    o.x = f2bf(a0); o.y = f2bf(a1); o.z = f2bf(a2); o.w = f2bf(a3);
    *(ushort4*)(H + (size_t)node * NHID + lane * 4) = o;
}

// ---------------- SpMM2 + bias + log_softmax (one wave/node, 1 class/lane, 8-way) ----------------

__global__ __launch_bounds__(256) void spmm_bias_lsm_kernel(
    const u16* __restrict__ S, const int* __restrict__ deg,
    const u32* __restrict__ csr, const float* __restrict__ bias,
    float* __restrict__ out, int n) {
    int node = blockIdx.x * 4 + (threadIdx.x >> 6);
    if (node >= n) return;
    node = __builtin_amdgcn_readfirstlane(node);
    int lane = threadIdx.x & 63;
    int beg = node * CSTRIDE;
    int end = beg + deg[node * DEGS];
    float acc = 0.f;
    int j = beg;
    for (; j + 8 <= end; j += 8) {
        u32 e[8];
        #pragma unroll
        for (int i = 0; i < 8; ++i) e[i] = csr[j + i];   // uniform -> s_load
        u16 v[8];
        #pragma unroll
        for (int i = 0; i < 8; ++i)
            v[i] = S[(size_t)(e[i] & 0xFFFFu) * NCLASS + lane];
        #pragma unroll
        for (int i = 0; i < 8; ++i)
            acc += bf2f((u16)(e[i] >> 16)) * bf2f(v[i]);
    }
    for (; j < end; ++j) {
        u32 e0 = csr[j];
        acc += bf2f((u16)(e0 >> 16)) * bf2f(S[(size_t)(e0 & 0xFFFFu) * NCLASS + lane]);
    }

    float x = acc + bias[lane];
    float m = x;
    #pragma unroll
    for (int off = 32; off > 0; off >>= 1) m = fmaxf(m, __shfl_xor(m, off));
    float e = expf(x - m);
    float ssum = e;
    #pragma unroll
    for (int off = 32; off > 0; off >>= 1) ssum += __shfl_xor(ssum, off);
    out[(size_t)node * NCLASS + lane] = x - m - logf(ssum);
}

// ---------------- launch ----------------

extern "C" void kernel_launch(void* const* d_in, const int* in_sizes, int n_in,
                              void* d_out, int out_size, void* d_ws, size_t ws_size,
                              hipStream_t stream) {
    const float* x  = (const float*)d_in[0];   // [50000,512]
    const float* W1 = (const float*)d_in[1];   // [512,256]
    const float* b1 = (const float*)d_in[2];   // [256]
    const float* W2 = (const float*)d_in[3];   // [256,64]
    const float* b2 = (const float*)d_in[4];   // [64]
    const float* ew = (const float*)d_in[5];   // [800000]
    const int* esrc = (const int*)d_in[6];
    const int* edst = (const int*)d_in[7];
    float* out = (float*)d_out;                // [50000,64]

    char* ws = (char*)d_ws;
    size_t off = 0;
    auto take = [&](size_t bytes) -> void* {
        off = (off + 255) & ~(size_t)255;
        void* p = ws + off;
        off += bytes;
        return p;
    };
    u16* S1  = (u16*)take((size_t)N_NODES * NHID * 2);          // 25.6 MB
    u16* H   = (u16*)take((size_t)N_NODES * NHID * 2);          // 25.6 MB
    u16* S2  = (u16*)take((size_t)N_NODES * NCLASS * 2);        // 6.4 MB
    u16* W1T = (u16*)take((size_t)NHID * NFEAT * 2);            // [256][512]
    u16* W2T = (u16*)take((size_t)NCLASS * NHID * 2);           // [64][256]
    int* deg = (int*)take((size_t)N_NODES * DEGS * 4);          // 3.2 MB padded
    u32* csr = (u32*)take((size_t)N_NODES * CSTRIDE * 4);       // 12.8 MB fixed-stride
    (void)ws_size; (void)in_sizes; (void)n_in; (void)out_size;

    prep0_kernel<<<PW1B + PW2B + DEGZB, 256, 0, stream>>>(W1, W1T, W2, W2T, deg);
    gemm1_scatter_kernel<<<GB1, 256, 0, stream>>>(x, W1T, S1, esrc, edst, ew,
                                                  deg, csr);
    spmm_bias_relu_kernel<<<(N_NODES + 3) / 4, 256, 0, stream>>>(
        S1, deg, csr, b1, H, N_NODES);
    gemm2_kernel<<<(N_NODES + 127) / 128, 256, 0, stream>>>(H, W2T, S2, N_NODES);
    spmm_bias_lsm_kernel<<<(N_NODES + 3) / 4, 256, 0, stream>>>(
        S2, deg, csr, b2, out, N_NODES);
}

// Round 5
// 298.754 us; speedup vs baseline: 1.0279x; 1.0279x over previous
//
#include <hip/hip_runtime.h>
#include <cstdint>

// GCN forward on MI355X (gfx950). f32 in/out; bf16 MFMA with fp32 accum;
// bf16 intermediates; 4-byte packed fixed-stride CSR (src:u16 | weight:bf16).
// Round 14:
//  - reverted scatter arrangement to R3 block-partition (R4 role-merge was
//    -7us worse; atomic stream doesn't overlap with GEMM either way).
//  - gemm2 FUSED into spmm1: a block gathers 16 nodes' H-rows (bias+relu) into
//    swizzled LDS (bf16, same rounding as before), then MFMAs vs W2T staged
//    like gemm_body -> S2 directly. H never touches HBM (-51.2MB traffic,
//    -1 dispatch). spmm2 unchanged.
// Chain (4): prep0 -> [scatter || gemm1(f32 A)] -> spmm1+bias+relu+gemm2
//   -> spmm2+bias+log_softmax.

typedef unsigned short u16;
typedef unsigned int u32;
typedef __attribute__((ext_vector_type(8))) short bf16x8;
typedef __attribute__((ext_vector_type(4))) float f32x4;

#define N_NODES 50000
#define N_EDGES 800000
#define NFEAT 512
#define NHID 256
#define NCLASS 64
#define CSTRIDE 64        // fixed CSR slots per node (max deg << 64)
#define DEGS 16           // deg stride in ints: one counter per 64B line

#define SB  391           // scatter blocks: ceil(800000/2048)
#define GB1 782           // gemm1 blocks: ceil(50000/64)
#define PW1B 512          // W1T transpose blocks
#define PW2B 64           // W2T transpose blocks
#define DEGZB 196         // deg-zero blocks: ceil(800000 ints / 4096)
#define FNB 3125          // fused spmm1+gemm2 blocks: 50000/16

__device__ __forceinline__ float bf2f(u16 h) {
    union { u32 u; float f; } c; c.u = ((u32)h) << 16; return c.f;
}
__device__ __forceinline__ u16 f2bf(float f) {
    union { float f; u32 u; } c; c.f = f;
    u32 u = c.u;
    return (u16)((u + 0x7fffu + ((u >> 16) & 1u)) >> 16);   // RNE
}
__device__ __forceinline__ u32 pk2(float a, float b) {
    return (u32)f2bf(a) | ((u32)f2bf(b) << 16);
}

// async global->LDS, 16B per lane; LDS dest = wave-uniform base + lane*16.
__device__ __forceinline__ void async16(const void* g, void* l) {
    __builtin_amdgcn_global_load_lds(
        (const __attribute__((address_space(1))) void*)(uintptr_t)g,
        (__attribute__((address_space(3))) void*)(uintptr_t)l, 16, 0, 0);
}

// ---------------- prep0: W1/W2 transpose+cvt + deg zeroing ----------------
// blocks [0,PW1B): W1T. [PW1B,PW1B+PW2B): W2T. rest: zero deg (16 ints/thread).

__global__ __launch_bounds__(256) void prep0_kernel(
    const float* __restrict__ W1, u16* __restrict__ W1T,
    const float* __restrict__ W2, u16* __restrict__ W2T,
    int* __restrict__ deg) {
    int b = blockIdx.x;
    if (b < PW1B) {
        int idx = b * 256 + threadIdx.x;           // W1T[256][512]
        int n = idx >> 9, k = idx & 511;
        W1T[idx] = f2bf(W1[(size_t)k * NHID + n]);
    } else if (b < PW1B + PW2B) {
        int idx = (b - PW1B) * 256 + threadIdx.x;  // W2T[64][256]
        int n = idx >> 8, k = idx & 255;
        W2T[idx] = f2bf(W2[(size_t)k * NCLASS + n]);
    } else {
        int base = (b - PW1B - PW2B) * 4096 + threadIdx.x * 16;
        if (base < N_NODES * DEGS) {               // 800000 % 16 == 0: full chunk
            int4 z = make_int4(0, 0, 0, 0);
            int4* p = (int4*)(deg + base);
            p[0] = z; p[1] = z; p[2] = z; p[3] = z;
        }
    }
}

// ---------------- shared GEMM body: C[M,NT] = A[M,K] @ BT[NT][K]^T ----------------
// Tiles in LDS are [row][64] u16 with the 16B-chunk index XOR-swizzled by row&7
// (T2). Async-staged operands keep the LDS dest linear and permute the global
// source chunk; the reg-staged (ACVT) A swizzles the ds_write address. Fragment
// reads apply the same XOR. 4 waves WROWSxWCOLS, BK=64 (2 k-halves).
// Epilogue repacks C through LDS.

template <int MT, int NT, int WCOLS, int K, bool ACVT>
__device__ __forceinline__ void gemm_body(const void* __restrict__ Av,
                                          const u16* __restrict__ BT,
                                          u16* __restrict__ C, int M,
                                          int bid, u16* lds) {
    constexpr int WROWS = 4 / WCOLS;
    constexpr int RT = MT / (16 * WROWS);
    constexpr int CT = NT / (16 * WCOLS);
    u16* As = lds;             // [MT][64] swizzled
    u16* Bs = lds + MT * 64;   // [NT][64] swizzled (B^T: row n, k-contig)

    const int tid  = threadIdx.x;
    const int wv   = tid >> 6, lane = tid & 63;
    const int lm   = lane & 15, quad = lane >> 4;
    const int wrow = wv / WCOLS, wcol = wv % WCOLS;
    const int m0   = bid * MT;
    // swizzled in-row u16 offsets for the 2 k-halves (row-bases are 0 mod 8,
    // so row&7 == lm&7 for every fragment row this lane touches)
    const int co0 = ((0 * 4 + quad) ^ (lm & 7)) * 8;
    const int co1 = ((1 * 4 + quad) ^ (lm & 7)) * 8;

    f32x4 acc[RT][CT];
    #pragma unroll
    for (int r = 0; r < RT; ++r)
        #pragma unroll
        for (int c = 0; c < CT; ++c) acc[r][c] = (f32x4){0.f, 0.f, 0.f, 0.f};

    for (int k0 = 0; k0 < K; k0 += 64) {
        if constexpr (ACVT) {
            static_assert(MT == 64, "ACVT staging assumes MT==64 (16 elems/thread)");
            const float* Af = (const float*)Av;
            // issue A f32 loads first (reg), then B DMA, then pack+write.
            int row = tid >> 2, ko = (tid & 3) * 16;   // ko: u16 offset, chunks 2q,2q+1
            int gr = m0 + row; if (gr > M - 1) gr = M - 1;
            const float4* gp = (const float4*)(Af + (size_t)gr * K + k0 + ko);
            float4 f0 = gp[0], f1 = gp[1], f2 = gp[2], f3 = gp[3];
            #pragma unroll
            for (int i = 0; i < NT / 32; ++i) {
                int c = i * 256 + tid;
                int n = c >> 3, kb = c & 7;
                async16(BT + (size_t)n * K + k0 + ((kb ^ (n & 7)) * 8), Bs + c * 8);
            }
            u32 p[8] = {pk2(f0.x, f0.y), pk2(f0.z, f0.w), pk2(f1.x, f1.y), pk2(f1.z, f1.w),
                        pk2(f2.x, f2.y), pk2(f2.z, f2.w), pk2(f3.x, f3.y), pk2(f3.z, f3.w)};
            int ch0 = (2 * (tid & 3))     ^ (row & 7);
            int ch1 = (2 * (tid & 3) + 1) ^ (row & 7);
            *(int4*)(As + row * 64 + ch0 * 8) = *(int4*)&p[0];
            *(int4*)(As + row * 64 + ch1 * 8) = *(int4*)&p[4];
        } else {
            const u16* A = (const u16*)Av;
            #pragma unroll
            for (int i = 0; i < NT / 32; ++i) {
                int c = i * 256 + tid;
                int n = c >> 3, kb = c & 7;
                async16(BT + (size_t)n * K + k0 + ((kb ^ (n & 7)) * 8), Bs + c * 8);
            }
            #pragma unroll
            for (int i = 0; i < MT / 32; ++i) {
                int c = i * 256 + tid;
                int row = c >> 3, kb = c & 7;
                int gr = m0 + row; if (gr > M - 1) gr = M - 1;
                async16(A + (size_t)gr * K + k0 + ((kb ^ (row & 7)) * 8), As + c * 8);
            }
        }
        __syncthreads();   // drains async vmcnt + lgkm (ds_write)

        #pragma unroll
        for (int kk = 0; kk < 2; ++kk) {
            const int co = kk ? co1 : co0;
            bf16x8 af[RT], bfv[CT];
            #pragma unroll
            for (int rt = 0; rt < RT; ++rt) {
                int row = wrow * (RT * 16) + rt * 16 + lm;
                af[rt] = *(const bf16x8*)(As + row * 64 + co);
            }
            #pragma unroll
            for (int ct = 0; ct < CT; ++ct) {
                int n = wcol * CT * 16 + ct * 16 + lm;
                bfv[ct] = *(const bf16x8*)(Bs + n * 64 + co);
            }
            #pragma unroll
            for (int rt = 0; rt < RT; ++rt)
                #pragma unroll
                for (int ct = 0; ct < CT; ++ct)
                    acc[rt][ct] = __builtin_amdgcn_mfma_f32_16x16x32_bf16(
                        af[rt], bfv[ct], acc[rt][ct], 0, 0, 0);
        }
        __syncthreads();
    }

    #pragma unroll
    for (int rt = 0; rt < RT; ++rt)
        #pragma unroll
        for (int ct = 0; ct < CT; ++ct) {
            int col = wcol * CT * 16 + ct * 16 + lm;
            #pragma unroll
            for (int r = 0; r < 4; ++r) {
                int row = wrow * (RT * 16) + rt * 16 + quad * 4 + r;  // C/D: row=quad*4+reg
                lds[row * NT + col] = f2bf(acc[rt][ct][r]);
            }
        }
    __syncthreads();
    constexpr int NC = MT * NT / 2048;
    #pragma unroll
    for (int i = 0; i < NC; ++i) {
        int c = i * 256 + tid;
        int row = (c * 8) / NT;
        if (m0 + row < M)
            *(int4*)(C + (size_t)m0 * NT + c * 8) = *(const int4*)(lds + c * 8);
    }
}

// ---------------- fused scatter || gemm1 (R3 arrangement) ----------------
// blocks [0,SB): 8 edges/thread; slot = atomicAdd(deg[dst*16]); csr write.
// blocks [SB,SB+GB1): gemm1 on f32 x with in-flight bf16 packing.

__global__ __launch_bounds__(256) void gemm1_scatter_kernel(
    const float* __restrict__ x, const u16* __restrict__ W1T, u16* __restrict__ S1,
    const int* __restrict__ esrc, const int* __restrict__ edst,
    const float* __restrict__ ew, int* __restrict__ deg, u32* __restrict__ csr) {
    __shared__ __align__(16) u16 lds[(64 + 256) * 64];
    int b = blockIdx.x;
    if (b < SB) {
        int e0 = (b * 256 + threadIdx.x) * 8;
        if (e0 < N_EDGES) {                       // 800000 % 8 == 0: full chunk
            int4 d0 = *(const int4*)(edst + e0),  d1 = *(const int4*)(edst + e0 + 4);
            int4 s0 = *(const int4*)(esrc + e0),  s1 = *(const int4*)(esrc + e0 + 4);
            float4 w0 = *(const float4*)(ew + e0), w1 = *(const float4*)(ew + e0 + 4);
            int d[8] = {d0.x, d0.y, d0.z, d0.w, d1.x, d1.y, d1.z, d1.w};
            int s[8] = {s0.x, s0.y, s0.z, s0.w, s1.x, s1.y, s1.z, s1.w};
            float w[8] = {w0.x, w0.y, w0.z, w0.w, w1.x, w1.y, w1.z, w1.w};
            int r[8];
            #pragma unroll
            for (int i = 0; i < 8; ++i)           // 8 independent atomics in flight
                r[i] = atomicAdd(&deg[d[i] * DEGS], 1);
            #pragma unroll
            for (int i = 0; i < 8; ++i)
                if (r[i] < CSTRIDE)               // safety clamp; never hit for this data
                    csr[(size_t)d[i] * CSTRIDE + r[i]] = (u32)s[i] | ((u32)f2bf(w[i]) << 16);
        }
    } else {
        gemm_body<64, 256, 4, NFEAT, true>(x, W1T, S1, N_NODES, b - SB, lds);
    }
}

// ---------------- fused SpMM1 + bias + ReLU + gemm2 ----------------
// Block = 256 threads = 4 waves = 16 nodes. Phase 1: wave wv gathers nodes
// lrow = wv*4+it (it=0..3), applies bias1+relu, writes bf16 H-row to swizzled
// LDS (chunk ^= lrow&7 over 32x16B chunks). Phase 2: 16x64x256 MFMA vs W2T
// (staged per-k0 like gemm_body), S2 written via small LDS repack.

__global__ __launch_bounds__(256) void spmm1_gemm2_kernel(
    const u16* __restrict__ S, const int* __restrict__ deg,
    const u32* __restrict__ csr, const float* __restrict__ bias1,
    const u16* __restrict__ W2T, u16* __restrict__ S2) {
    __shared__ __align__(16) u16 Hs[16 * 256];   // [16][256] swizzled; reused for S2 repack
    __shared__ __align__(16) u16 Bs[64 * 64];    // [64][64] swizzled

    const int tid  = threadIdx.x;
    const int wv   = tid >> 6, lane = tid & 63;
    const int lm   = lane & 15, quad = lane >> 4;
    const int b    = blockIdx.x;

    float4 bv = *(const float4*)(bias1 + lane * 4);

    // ---- phase 1: gather 4 nodes per wave ----
    #pragma unroll
    for (int it = 0; it < 4; ++it) {
        int lrow = wv * 4 + it;
        int node = __builtin_amdgcn_readfirstlane(b * 16 + lrow);
        int beg = node * CSTRIDE;
        int end = beg + deg[node * DEGS];
        float a0 = 0.f, a1 = 0.f, a2 = 0.f, a3 = 0.f;
        int j = beg;
        for (; j + 8 <= end; j += 8) {           // 8 outstanding gathers
            u32 e[8];
            #pragma unroll
            for (int i = 0; i < 8; ++i) e[i] = csr[j + i];   // uniform -> s_load
            ushort4 v[8];
            #pragma unroll
            for (int i = 0; i < 8; ++i)
                v[i] = *(const ushort4*)(S + (size_t)(e[i] & 0xFFFFu) * NHID + lane * 4);
            #pragma unroll
            for (int i = 0; i < 8; ++i) {
                float w = bf2f((u16)(e[i] >> 16));
                a0 += w * bf2f(v[i].x); a1 += w * bf2f(v[i].y);
                a2 += w * bf2f(v[i].z); a3 += w * bf2f(v[i].w);
            }
        }
        for (; j < end; ++j) {
            u32 e0 = csr[j];
            float w = bf2f((u16)(e0 >> 16));
            ushort4 v0 = *(const ushort4*)(S + (size_t)(e0 & 0xFFFFu) * NHID + lane * 4);
            a0 += w * bf2f(v0.x); a1 += w * bf2f(v0.y);
            a2 += w * bf2f(v0.z); a3 += w * bf2f(v0.w);
        }
        a0 = fmaxf(a0 + bv.x, 0.f);
        a1 = fmaxf(a1 + bv.y, 0.f);
        a2 = fmaxf(a2 + bv.z, 0.f);
        a3 = fmaxf(a3 + bv.w, 0.f);
        // lane holds feats [lane*4, lane*4+4) -> chunk = lane>>1, half = lane&1
        int ch = (lane >> 1) ^ (lrow & 7);
        u32* dp = (u32*)(Hs + lrow * 256 + ch * 8 + (lane & 1) * 4);
        dp[0] = pk2(a0, a1);
        dp[1] = pk2(a2, a3);
    }
    __syncthreads();

    // ---- phase 2: S2[16][64] = H[16][256] @ W2T[64][256]^T ----
    f32x4 acc = (f32x4){0.f, 0.f, 0.f, 0.f};
    for (int k0 = 0; k0 < NHID; k0 += 64) {
        #pragma unroll
        for (int i = 0; i < 2; ++i) {            // stage Bs: 512 chunks of 16B
            int c = i * 256 + tid;
            int n = c >> 3, kb = c & 7;
            async16(W2T + (size_t)n * NHID + k0 + ((kb ^ (n & 7)) * 8), Bs + c * 8);
        }
        __syncthreads();
        #pragma unroll
        for (int kk = 0; kk < 2; ++kk) {
            // A-frag: row lm of Hs, chunk = k0/8 + kk*4 + quad (of 32), ^ row&7
            int ca = ((k0 >> 3) + kk * 4 + quad) ^ (lm & 7);
            bf16x8 af = *(const bf16x8*)(Hs + lm * 256 + ca * 8);
            // B-frag: row n of Bs (8 chunks/row), chunk = kk*4+quad, ^ n&7
            int n = wv * 16 + lm;
            int cb = (kk * 4 + quad) ^ (n & 7);
            bf16x8 bf = *(const bf16x8*)(Bs + n * 64 + cb * 8);
            acc = __builtin_amdgcn_mfma_f32_16x16x32_bf16(af, bf, acc, 0, 0, 0);
        }
        __syncthreads();
    }

    // ---- epilogue: repack through LDS, linear store ----
    #pragma unroll
    for (int r = 0; r < 4; ++r) {
        int row = quad * 4 + r;                  // C/D: row = quad*4 + reg
        Hs[row * 64 + wv * 16 + lm] = f2bf(acc[r]);
    }
    __syncthreads();
    *(ushort4*)(S2 + (size_t)b * 1024 + tid * 4) = *(const ushort4*)(Hs + tid * 4);
}

// ---------------- SpMM2 + bias + log_softmax (one wave/node, 1 class/lane, 8-way) ----------------

__global__ __launch_bounds__(256) void spmm_bias_lsm_kernel(
    const u16* __restrict__ S, const int* __restrict__ deg,
    const u32* __restrict__ csr, const float* __restrict__ bias,
    float* __restrict__ out, int n) {
    int node = blockIdx.x * 4 + (threadIdx.x >> 6);
    if (node >= n) return;
    node = __builtin_amdgcn_readfirstlane(node);
    int lane = threadIdx.x & 63;
    int beg = node * CSTRIDE;
    int end = beg + deg[node * DEGS];
    float acc = 0.f;
    int j = beg;
    for (; j + 8 <= end; j += 8) {
        u32 e[8];
        #pragma unroll
        for (int i = 0; i < 8; ++i) e[i] = csr[j + i];   // uniform -> s_load
        u16 v[8];
        #pragma unroll
        for (int i = 0; i < 8; ++i)
            v[i] = S[(size_t)(e[i] & 0xFFFFu) * NCLASS + lane];
        #pragma unroll
        for (int i = 0; i < 8; ++i)
            acc += bf2f((u16)(e[i] >> 16)) * bf2f(v[i]);
    }
    for (; j < end; ++j) {
        u32 e0 = csr[j];
        acc += bf2f((u16)(e0 >> 16)) * bf2f(S[(size_t)(e0 & 0xFFFFu) * NCLASS + lane]);
    }

    float x = acc + bias[lane];
    float m = x;
    #pragma unroll
    for (int off = 32; off > 0; off >>= 1) m = fmaxf(m, __shfl_xor(m, off));
    float e = expf(x - m);
    float ssum = e;
    #pragma unroll
    for (int off = 32; off > 0; off >>= 1) ssum += __shfl_xor(ssum, off);
    out[(size_t)node * NCLASS + lane] = x - m - logf(ssum);
}

// ---------------- launch ----------------

extern "C" void kernel_launch(void* const* d_in, const int* in_sizes, int n_in,
                              void* d_out, int out_size, void* d_ws, size_t ws_size,
                              hipStream_t stream) {
    const float* x  = (const float*)d_in[0];   // [50000,512]
    const float* W1 = (const float*)d_in[1];   // [512,256]
    const float* b1 = (const float*)d_in[2];   // [256]
    const float* W2 = (const float*)d_in[3];   // [256,64]
    const float* b2 = (const float*)d_in[4];   // [64]
    const float* ew = (const float*)d_in[5];   // [800000]
    const int* esrc = (const int*)d_in[6];
    const int* edst = (const int*)d_in[7];
    float* out = (float*)d_out;                // [50000,64]

    char* ws = (char*)d_ws;
    size_t off = 0;
    auto take = [&](size_t bytes) -> void* {
        off = (off + 255) & ~(size_t)255;
        void* p = ws + off;
        off += bytes;
        return p;
    };
    u16* S1  = (u16*)take((size_t)N_NODES * NHID * 2);          // 25.6 MB
    u16* S2  = (u16*)take((size_t)N_NODES * NCLASS * 2);        // 6.4 MB
    u16* W1T = (u16*)take((size_t)NHID * NFEAT * 2);            // [256][512]
    u16* W2T = (u16*)take((size_t)NCLASS * NHID * 2);           // [64][256]
    int* deg = (int*)take((size_t)N_NODES * DEGS * 4);          // 3.2 MB padded
    u32* csr = (u32*)take((size_t)N_NODES * CSTRIDE * 4);       // 12.8 MB fixed-stride
    (void)ws_size; (void)in_sizes; (void)n_in; (void)out_size;

    prep0_kernel<<<PW1B + PW2B + DEGZB, 256, 0, stream>>>(W1, W1T, W2, W2T, deg);
    gemm1_scatter_kernel<<<SB + GB1, 256, 0, stream>>>(x, W1T, S1, esrc, edst, ew,
                                                       deg, csr);
    spmm1_gemm2_kernel<<<FNB, 256, 0, stream>>>(S1, deg, csr, b1, W2T, S2);
    spmm_bias_lsm_kernel<<<(N_NODES + 3) / 4, 256, 0, stream>>>(
        S2, deg, csr, b2, out, N_NODES);
}

// Round 6
// 288.920 us; speedup vs baseline: 1.0629x; 1.0340x over previous
//
#include <hip/hip_runtime.h>
#include <cstdint>

// GCN forward on MI355X (gfx950). f32 in/out; bf16 MFMA with fp32 accum;
// bf16 intermediates; 4-byte packed fixed-stride CSR (src:u16 | weight:bf16).
// Round 15: two-level bucket CSR build replaces the 800k-device-atomic scatter.
//  - Pass A (fused w/ gemm1): blocks rank 2048 edges in LDS over 196 coarse
//    buckets (dst>>8), flush ONE global atomicAdd per (block,bucket) (77k
//    device atomics, 10x fewer), write u64 entries to static bucket regions.
//  - Pass B (csr_sort): per-bucket LDS counting-rank -> fixed-stride csr +
//    non-atomic coalesced deg. deg padding removed.
// Chain (5): prep0 -> [bucketA || gemm1(f32 A)] -> csr_sort ->
//   spmm1+bias+relu+gemm2 -> spmm2+bias+log_softmax.

typedef unsigned short u16;
typedef unsigned int u32;
typedef unsigned long long u64;
typedef __attribute__((ext_vector_type(8))) short bf16x8;
typedef __attribute__((ext_vector_type(4))) float f32x4;

#define N_NODES 50000
#define N_EDGES 800000
#define NFEAT 512
#define NHID 256
#define NCLASS 64
#define CSTRIDE 64        // fixed CSR slots per node (max deg << 64)

#define NBUCK 196         // coarse buckets: dst>>8 (50000/256)
#define BCAP 5120         // bucket region capacity (mean 4096 + 16 sigma)
#define SCB 391           // bucket-scatter blocks: ceil(800000/2048)
#define GB1 782           // gemm1 blocks: ceil(50000/64)
#define PW1B 512          // W1T transpose blocks
#define PW2B 64           // W2T transpose blocks
#define FNB 3125          // fused spmm1+gemm2 blocks: 50000/16

__device__ __forceinline__ float bf2f(u16 h) {
    union { u32 u; float f; } c; c.u = ((u32)h) << 16; return c.f;
}
__device__ __forceinline__ u16 f2bf(float f) {
    union { float f; u32 u; } c; c.f = f;
    u32 u = c.u;
    return (u16)((u + 0x7fffu + ((u >> 16) & 1u)) >> 16);   // RNE
}
__device__ __forceinline__ u32 pk2(float a, float b) {
    return (u32)f2bf(a) | ((u32)f2bf(b) << 16);
}

// async global->LDS, 16B per lane; LDS dest = wave-uniform base + lane*16.
__device__ __forceinline__ void async16(const void* g, void* l) {
    __builtin_amdgcn_global_load_lds(
        (const __attribute__((address_space(1))) void*)(uintptr_t)g,
        (__attribute__((address_space(3))) void*)(uintptr_t)l, 16, 0, 0);
}

// ---------------- prep0: W1/W2 transpose+cvt + fill zeroing ----------------
// blocks [0,PW1B): W1T. [PW1B,PW1B+PW2B): W2T. last block: zero fill[196].

__global__ __launch_bounds__(256) void prep0_kernel(
    const float* __restrict__ W1, u16* __restrict__ W1T,
    const float* __restrict__ W2, u16* __restrict__ W2T,
    int* __restrict__ fill) {
    int b = blockIdx.x;
    if (b < PW1B) {
        int idx = b * 256 + threadIdx.x;           // W1T[256][512]
        int n = idx >> 9, k = idx & 511;
        W1T[idx] = f2bf(W1[(size_t)k * NHID + n]);
    } else if (b < PW1B + PW2B) {
        int idx = (b - PW1B) * 256 + threadIdx.x;  // W2T[64][256]
        int n = idx >> 8, k = idx & 255;
        W2T[idx] = f2bf(W2[(size_t)k * NCLASS + n]);
    } else {
        if (threadIdx.x < NBUCK) fill[threadIdx.x] = 0;
    }
}

// ---------------- shared GEMM body: C[M,NT] = A[M,K] @ BT[NT][K]^T ----------------
// Tiles in LDS are [row][64] u16 with the 16B-chunk index XOR-swizzled by row&7
// (T2). Async-staged operands keep the LDS dest linear and permute the global
// source chunk; the reg-staged (ACVT) A swizzles the ds_write address. Fragment
// reads apply the same XOR. 4 waves WROWSxWCOLS, BK=64 (2 k-halves).
// Epilogue repacks C through LDS.

template <int MT, int NT, int WCOLS, int K, bool ACVT>
__device__ __forceinline__ void gemm_body(const void* __restrict__ Av,
                                          const u16* __restrict__ BT,
                                          u16* __restrict__ C, int M,
                                          int bid, u16* lds) {
    constexpr int WROWS = 4 / WCOLS;
    constexpr int RT = MT / (16 * WROWS);
    constexpr int CT = NT / (16 * WCOLS);
    u16* As = lds;             // [MT][64] swizzled
    u16* Bs = lds + MT * 64;   // [NT][64] swizzled (B^T: row n, k-contig)

    const int tid  = threadIdx.x;
    const int wv   = tid >> 6, lane = tid & 63;
    const int lm   = lane & 15, quad = lane >> 4;
    const int wrow = wv / WCOLS, wcol = wv % WCOLS;
    const int m0   = bid * MT;
    // swizzled in-row u16 offsets for the 2 k-halves (row-bases are 0 mod 8,
    // so row&7 == lm&7 for every fragment row this lane touches)
    const int co0 = ((0 * 4 + quad) ^ (lm & 7)) * 8;
    const int co1 = ((1 * 4 + quad) ^ (lm & 7)) * 8;

    f32x4 acc[RT][CT];
    #pragma unroll
    for (int r = 0; r < RT; ++r)
        #pragma unroll
        for (int c = 0; c < CT; ++c) acc[r][c] = (f32x4){0.f, 0.f, 0.f, 0.f};

    for (int k0 = 0; k0 < K; k0 += 64) {
        if constexpr (ACVT) {
            static_assert(MT == 64, "ACVT staging assumes MT==64 (16 elems/thread)");
            const float* Af = (const float*)Av;
            // issue A f32 loads first (reg), then B DMA, then pack+write.
            int row = tid >> 2, ko = (tid & 3) * 16;   // ko: u16 offset, chunks 2q,2q+1
            int gr = m0 + row; if (gr > M - 1) gr = M - 1;
            const float4* gp = (const float4*)(Af + (size_t)gr * K + k0 + ko);
            float4 f0 = gp[0], f1 = gp[1], f2 = gp[2], f3 = gp[3];
            #pragma unroll
            for (int i = 0; i < NT / 32; ++i) {
                int c = i * 256 + tid;
                int n = c >> 3, kb = c & 7;
                async16(BT + (size_t)n * K + k0 + ((kb ^ (n & 7)) * 8), Bs + c * 8);
            }
            u32 p[8] = {pk2(f0.x, f0.y), pk2(f0.z, f0.w), pk2(f1.x, f1.y), pk2(f1.z, f1.w),
                        pk2(f2.x, f2.y), pk2(f2.z, f2.w), pk2(f3.x, f3.y), pk2(f3.z, f3.w)};
            int ch0 = (2 * (tid & 3))     ^ (row & 7);
            int ch1 = (2 * (tid & 3) + 1) ^ (row & 7);
            *(int4*)(As + row * 64 + ch0 * 8) = *(int4*)&p[0];
            *(int4*)(As + row * 64 + ch1 * 8) = *(int4*)&p[4];
        } else {
            const u16* A = (const u16*)Av;
            #pragma unroll
            for (int i = 0; i < NT / 32; ++i) {
                int c = i * 256 + tid;
                int n = c >> 3, kb = c & 7;
                async16(BT + (size_t)n * K + k0 + ((kb ^ (n & 7)) * 8), Bs + c * 8);
            }
            #pragma unroll
            for (int i = 0; i < MT / 32; ++i) {
                int c = i * 256 + tid;
                int row = c >> 3, kb = c & 7;
                int gr = m0 + row; if (gr > M - 1) gr = M - 1;
                async16(A + (size_t)gr * K + k0 + ((kb ^ (row & 7)) * 8), As + c * 8);
            }
        }
        __syncthreads();   // drains async vmcnt + lgkm (ds_write)

        #pragma unroll
        for (int kk = 0; kk < 2; ++kk) {
            const int co = kk ? co1 : co0;
            bf16x8 af[RT], bfv[CT];
            #pragma unroll
            for (int rt = 0; rt < RT; ++rt) {
                int row = wrow * (RT * 16) + rt * 16 + lm;
                af[rt] = *(const bf16x8*)(As + row * 64 + co);
            }
            #pragma unroll
            for (int ct = 0; ct < CT; ++ct) {
                int n = wcol * CT * 16 + ct * 16 + lm;
                bfv[ct] = *(const bf16x8*)(Bs + n * 64 + co);
            }
            #pragma unroll
            for (int rt = 0; rt < RT; ++rt)
                #pragma unroll
                for (int ct = 0; ct < CT; ++ct)
                    acc[rt][ct] = __builtin_amdgcn_mfma_f32_16x16x32_bf16(
                        af[rt], bfv[ct], acc[rt][ct], 0, 0, 0);
        }
        __syncthreads();
    }

    #pragma unroll
    for (int rt = 0; rt < RT; ++rt)
        #pragma unroll
        for (int ct = 0; ct < CT; ++ct) {
            int col = wcol * CT * 16 + ct * 16 + lm;
            #pragma unroll
            for (int r = 0; r < 4; ++r) {
                int row = wrow * (RT * 16) + rt * 16 + quad * 4 + r;  // C/D: row=quad*4+reg
                lds[row * NT + col] = f2bf(acc[rt][ct][r]);
            }
        }
    __syncthreads();
    constexpr int NC = MT * NT / 2048;
    #pragma unroll
    for (int i = 0; i < NC; ++i) {
        int c = i * 256 + tid;
        int row = (c * 8) / NT;
        if (m0 + row < M)
            *(int4*)(C + (size_t)m0 * NT + c * 8) = *(const int4*)(lds + c * 8);
    }
}

// ---------------- fused bucket-scatter || gemm1 ----------------
// blocks [0,SCB): 2048 edges/block. LDS-rank over 196 buckets (dst>>8), one
// global atomicAdd per (block,bucket), u64 entries -> static bucket regions.
// blocks [SCB,SCB+GB1): gemm1 on f32 x with in-flight bf16 packing.

__global__ __launch_bounds__(256) void gemm1_scatter_kernel(
    const float* __restrict__ x, const u16* __restrict__ W1T, u16* __restrict__ S1,
    const int* __restrict__ esrc, const int* __restrict__ edst,
    const float* __restrict__ ew, int* __restrict__ fill, u64* __restrict__ region) {
    __shared__ __align__(16) u16 lds[(64 + 256) * 64];
    int b = blockIdx.x;
    int tid = threadIdx.x;
    if (b < SCB) {
        int* cnt  = (int*)lds;          // [196]
        int* base = cnt + NBUCK;        // [196]
        if (tid < NBUCK) cnt[tid] = 0;
        __syncthreads();
        int e0 = b * 2048 + tid * 8;
        int d[8], s[8], rk[8];
        float w[8];
        bool act = (e0 < N_EDGES);      // partial tail block: full 8-chunks only
        if (act) {
            int4 d0 = *(const int4*)(edst + e0),  d1 = *(const int4*)(edst + e0 + 4);
            int4 s0 = *(const int4*)(esrc + e0),  s1 = *(const int4*)(esrc + e0 + 4);
            float4 w0 = *(const float4*)(ew + e0), w1 = *(const float4*)(ew + e0 + 4);
            d[0]=d0.x; d[1]=d0.y; d[2]=d0.z; d[3]=d0.w;
            d[4]=d1.x; d[5]=d1.y; d[6]=d1.z; d[7]=d1.w;
            s[0]=s0.x; s[1]=s0.y; s[2]=s0.z; s[3]=s0.w;
            s[4]=s1.x; s[5]=s1.y; s[6]=s1.z; s[7]=s1.w;
            w[0]=w0.x; w[1]=w0.y; w[2]=w0.z; w[3]=w0.w;
            w[4]=w1.x; w[5]=w1.y; w[6]=w1.z; w[7]=w1.w;
            #pragma unroll
            for (int i = 0; i < 8; ++i)
                rk[i] = atomicAdd(&cnt[d[i] >> 8], 1);   // LDS atomic: block-local rank
        }
        __syncthreads();
        if (tid < NBUCK) base[tid] = atomicAdd(&fill[tid], cnt[tid]);
        __syncthreads();
        if (act) {
            #pragma unroll
            for (int i = 0; i < 8; ++i) {
                int g = d[i] >> 8;
                int pos = base[g] + rk[i];
                if (pos < BCAP) {
                    u64 en = ((u64)(d[i] & 255) << 32) |
                             (u64)((u32)s[i] | ((u32)f2bf(w[i]) << 16));
                    region[(size_t)g * BCAP + pos] = en;
                }
            }
        }
    } else {
        gemm_body<64, 256, 4, NFEAT, true>(x, W1T, S1, N_NODES, b - SCB, lds);
    }
}

// ---------------- csr_sort: per-bucket LDS counting-rank -> fixed-stride csr ----------------
// 196 blocks, one 256-node bucket each. deg written non-atomically, coalesced.

__global__ __launch_bounds__(256) void csr_sort_kernel(
    const u64* __restrict__ region, const int* __restrict__ fill,
    u32* __restrict__ csr, int* __restrict__ deg) {
    __shared__ int cnt2[256];
    int b = blockIdx.x, tid = threadIdx.x;
    cnt2[tid] = 0;
    __syncthreads();
    int Eb = fill[b]; if (Eb > BCAP) Eb = BCAP;
    for (int i = tid; i < Eb; i += 256) {
        u64 en = region[(size_t)b * BCAP + i];
        int dlo = (int)(en >> 32) & 255;
        int r = atomicAdd(&cnt2[dlo], 1);
        if (r < CSTRIDE)
            csr[(size_t)(b * 256 + dlo) * CSTRIDE + r] = (u32)en;
    }
    __syncthreads();
    int node = b * 256 + tid;
    if (node < N_NODES) {
        int dg = cnt2[tid]; if (dg > CSTRIDE) dg = CSTRIDE;
        deg[node] = dg;
    }
}

// ---------------- fused SpMM1 + bias + ReLU + gemm2 ----------------
// Block = 256 threads = 4 waves = 16 nodes. Phase 1: wave wv gathers nodes
// lrow = wv*4+it (it=0..3), applies bias1+relu, writes bf16 H-row to swizzled
// LDS (chunk ^= lrow&7 over 32x16B chunks). Phase 2: 16x64x256 MFMA vs W2T
// (staged per-k0 like gemm_body), S2 written via small LDS repack.

__global__ __launch_bounds__(256) void spmm1_gemm2_kernel(
    const u16* __restrict__ S, const int* __restrict__ deg,
    const u32* __restrict__ csr, const float* __restrict__ bias1,
    const u16* __restrict__ W2T, u16* __restrict__ S2) {
    __shared__ __align__(16) u16 Hs[16 * 256];   // [16][256] swizzled; reused for S2 repack
    __shared__ __align__(16) u16 Bs[64 * 64];    // [64][64] swizzled

    const int tid  = threadIdx.x;
    const int wv   = tid >> 6, lane = tid & 63;
    const int lm   = lane & 15, quad = lane >> 4;
    const int b    = blockIdx.x;

    float4 bv = *(const float4*)(bias1 + lane * 4);

    // ---- phase 1: gather 4 nodes per wave ----
    #pragma unroll
    for (int it = 0; it < 4; ++it) {
        int lrow = wv * 4 + it;
        int node = __builtin_amdgcn_readfirstlane(b * 16 + lrow);
        int beg = node * CSTRIDE;
        int end = beg + deg[node];
        float a0 = 0.f, a1 = 0.f, a2 = 0.f, a3 = 0.f;
        int j = beg;
        for (; j + 8 <= end; j += 8) {           // 8 outstanding gathers
            u32 e[8];
            #pragma unroll
            for (int i = 0; i < 8; ++i) e[i] = csr[j + i];   // uniform -> s_load
            ushort4 v[8];
            #pragma unroll
            for (int i = 0; i < 8; ++i)
                v[i] = *(const ushort4*)(S + (size_t)(e[i] & 0xFFFFu) * NHID + lane * 4);
            #pragma unroll
            for (int i = 0; i < 8; ++i) {
                float w = bf2f((u16)(e[i] >> 16));
                a0 += w * bf2f(v[i].x); a1 += w * bf2f(v[i].y);
                a2 += w * bf2f(v[i].z); a3 += w * bf2f(v[i].w);
            }
        }
        for (; j < end; ++j) {
            u32 e0 = csr[j];
            float w = bf2f((u16)(e0 >> 16));
            ushort4 v0 = *(const ushort4*)(S + (size_t)(e0 & 0xFFFFu) * NHID + lane * 4);
            a0 += w * bf2f(v0.x); a1 += w * bf2f(v0.y);
            a2 += w * bf2f(v0.z); a3 += w * bf2f(v0.w);
        }
        a0 = fmaxf(a0 + bv.x, 0.f);
        a1 = fmaxf(a1 + bv.y, 0.f);
        a2 = fmaxf(a2 + bv.z, 0.f);
        a3 = fmaxf(a3 + bv.w, 0.f);
        // lane holds feats [lane*4, lane*4+4) -> chunk = lane>>1, half = lane&1
        int ch = (lane >> 1) ^ (lrow & 7);
        u32* dp = (u32*)(Hs + lrow * 256 + ch * 8 + (lane & 1) * 4);
        dp[0] = pk2(a0, a1);
        dp[1] = pk2(a2, a3);
    }
    __syncthreads();

    // ---- phase 2: S2[16][64] = H[16][256] @ W2T[64][256]^T ----
    f32x4 acc = (f32x4){0.f, 0.f, 0.f, 0.f};
    for (int k0 = 0; k0 < NHID; k0 += 64) {
        #pragma unroll
        for (int i = 0; i < 2; ++i) {            // stage Bs: 512 chunks of 16B
            int c = i * 256 + tid;
            int n = c >> 3, kb = c & 7;
            async16(W2T + (size_t)n * NHID + k0 + ((kb ^ (n & 7)) * 8), Bs + c * 8);
        }
        __syncthreads();
        #pragma unroll
        for (int kk = 0; kk < 2; ++kk) {
            // A-frag: row lm of Hs, chunk = k0/8 + kk*4 + quad (of 32), ^ row&7
            int ca = ((k0 >> 3) + kk * 4 + quad) ^ (lm & 7);
            bf16x8 af = *(const bf16x8*)(Hs + lm * 256 + ca * 8);
            // B-frag: row n of Bs (8 chunks/row), chunk = kk*4+quad, ^ n&7
            int n = wv * 16 + lm;
            int cb = (kk * 4 + quad) ^ (n & 7);
            bf16x8 bf = *(const bf16x8*)(Bs + n * 64 + cb * 8);
            acc = __builtin_amdgcn_mfma_f32_16x16x32_bf16(af, bf, acc, 0, 0, 0);
        }
        __syncthreads();
    }

    // ---- epilogue: repack through LDS, linear store ----
    #pragma unroll
    for (int r = 0; r < 4; ++r) {
        int row = quad * 4 + r;                  // C/D: row = quad*4 + reg
        Hs[row * 64 + wv * 16 + lm] = f2bf(acc[r]);
    }
    __syncthreads();
    *(ushort4*)(S2 + (size_t)b * 1024 + tid * 4) = *(const ushort4*)(Hs + tid * 4);
}

// ---------------- SpMM2 + bias + log_softmax (one wave/node, 1 class/lane, 8-way) ----------------

__global__ __launch_bounds__(256) void spmm_bias_lsm_kernel(
    const u16* __restrict__ S, const int* __restrict__ deg,
    const u32* __restrict__ csr, const float* __restrict__ bias,
    float* __restrict__ out, int n) {
    int node = blockIdx.x * 4 + (threadIdx.x >> 6);
    if (node >= n) return;
    node = __builtin_amdgcn_readfirstlane(node);
    int lane = threadIdx.x & 63;
    int beg = node * CSTRIDE;
    int end = beg + deg[node];
    float acc = 0.f;
    int j = beg;
    for (; j + 8 <= end; j += 8) {
        u32 e[8];
        #pragma unroll
        for (int i = 0; i < 8; ++i) e[i] = csr[j + i];   // uniform -> s_load
        u16 v[8];
        #pragma unroll
        for (int i = 0; i < 8; ++i)
            v[i] = S[(size_t)(e[i] & 0xFFFFu) * NCLASS + lane];
        #pragma unroll
        for (int i = 0; i < 8; ++i)
            acc += bf2f((u16)(e[i] >> 16)) * bf2f(v[i]);
    }
    for (; j < end; ++j) {
        u32 e0 = csr[j];
        acc += bf2f((u16)(e0 >> 16)) * bf2f(S[(size_t)(e0 & 0xFFFFu) * NCLASS + lane]);
    }

    float x = acc + bias[lane];
    float m = x;
    #pragma unroll
    for (int off = 32; off > 0; off >>= 1) m = fmaxf(m, __shfl_xor(m, off));
    float e = expf(x - m);
    float ssum = e;
    #pragma unroll
    for (int off = 32; off > 0; off >>= 1) ssum += __shfl_xor(ssum, off);
    out[(size_t)node * NCLASS + lane] = x - m - logf(ssum);
}

// ---------------- launch ----------------

extern "C" void kernel_launch(void* const* d_in, const int* in_sizes, int n_in,
                              void* d_out, int out_size, void* d_ws, size_t ws_size,
                              hipStream_t stream) {
    const float* x  = (const float*)d_in[0];   // [50000,512]
    const float* W1 = (const float*)d_in[1];   // [512,256]
    const float* b1 = (const float*)d_in[2];   // [256]
    const float* W2 = (const float*)d_in[3];   // [256,64]
    const float* b2 = (const float*)d_in[4];   // [64]
    const float* ew = (const float*)d_in[5];   // [800000]
    const int* esrc = (const int*)d_in[6];
    const int* edst = (const int*)d_in[7];
    float* out = (float*)d_out;                // [50000,64]

    char* ws = (char*)d_ws;
    size_t off = 0;
    auto take = [&](size_t bytes) -> void* {
        off = (off + 255) & ~(size_t)255;
        void* p = ws + off;
        off += bytes;
        return p;
    };
    u16* S1   = (u16*)take((size_t)N_NODES * NHID * 2);          // 25.6 MB
    u16* S2   = (u16*)take((size_t)N_NODES * NCLASS * 2);        // 6.4 MB
    u16* W1T  = (u16*)take((size_t)NHID * NFEAT * 2);            // [256][512]
    u16* W2T  = (u16*)take((size_t)NCLASS * NHID * 2);           // [64][256]
    int* deg  = (int*)take((size_t)N_NODES * 4);                 // 0.2 MB
    u32* csr  = (u32*)take((size_t)N_NODES * CSTRIDE * 4);       // 12.8 MB fixed-stride
    int* fill = (int*)take((size_t)NBUCK * 4);
    u64* region = (u64*)take((size_t)NBUCK * BCAP * 8);          // 8.03 MB
    (void)ws_size; (void)in_sizes; (void)n_in; (void)out_size;

    prep0_kernel<<<PW1B + PW2B + 1, 256, 0, stream>>>(W1, W1T, W2, W2T, fill);
    gemm1_scatter_kernel<<<SCB + GB1, 256, 0, stream>>>(x, W1T, S1, esrc, edst, ew,
                                                        fill, region);
    csr_sort_kernel<<<NBUCK, 256, 0, stream>>>(region, fill, csr, deg);
    spmm1_gemm2_kernel<<<FNB, 256, 0, stream>>>(S1, deg, csr, b1, W2T, S2);
    spmm_bias_lsm_kernel<<<(N_NODES + 3) / 4, 256, 0, stream>>>(
        S2, deg, csr, b2, out, N_NODES);
}